// Round 6
// baseline (706.323 us; speedup 1.0000x reference)
//
#include <hip/hip_runtime.h>
#include <cmath>

#define CH 32
#define NBASIS 8
#define NPATH 11

__device__ __forceinline__ float silu_f(float x) {
    return x / (1.0f + __expf(-x));
}

// ---------- CSR build ----------
__global__ __launch_bounds__(256) void hist_kernel(const int* __restrict__ idx_i,
                                                   int* __restrict__ counts, int E) {
    int e = blockIdx.x * blockDim.x + threadIdx.x;
    if (e < E) atomicAdd(&counts[idx_i[e]], 1);
}

// 1024 counts per block -> bsum[b]
__global__ __launch_bounds__(256) void partial_kernel(const int* __restrict__ counts,
                                                      int* __restrict__ bsum, int N) {
    int base = blockIdx.x * 1024;
    int s = 0;
#pragma unroll
    for (int k = 0; k < 4; k++) {
        int i = base + k * 256 + threadIdx.x;
        if (i < N) s += counts[i];
    }
#pragma unroll
    for (int off = 32; off > 0; off >>= 1) s += __shfl_down(s, off);
    __shared__ int wsum[4];
    if ((threadIdx.x & 63) == 0) wsum[threadIdx.x >> 6] = s;
    __syncthreads();
    if (threadIdx.x == 0) bsum[blockIdx.x] = wsum[0] + wsum[1] + wsum[2] + wsum[3];
}

__global__ void scan_small(const int* __restrict__ bsum, int* __restrict__ bbase, int nb) {
    if (threadIdx.x == 0) {
        int acc = 0;
        for (int i = 0; i < nb; i++) { bbase[i] = acc; acc += bsum[i]; }
    }
}

__global__ __launch_bounds__(256) void offsets_kernel(const int* __restrict__ counts,
                                                      const int* __restrict__ bbase,
                                                      int* __restrict__ offsets,
                                                      int* __restrict__ cursor, int N) {
    int b = blockIdx.x;
    int base = b * 1024;
    int c[4];
    int s = 0;
#pragma unroll
    for (int k = 0; k < 4; k++) {
        int i = base + threadIdx.x * 4 + k;
        c[k] = (i < N) ? counts[i] : 0;
        s += c[k];
    }
    __shared__ int sc[256];
    sc[threadIdx.x] = s;
    __syncthreads();
    for (int off = 1; off < 256; off <<= 1) {
        int v = (threadIdx.x >= off) ? sc[threadIdx.x - off] : 0;
        __syncthreads();
        sc[threadIdx.x] += v;
        __syncthreads();
    }
    int excl = bbase[b] + sc[threadIdx.x] - s;
#pragma unroll
    for (int k = 0; k < 4; k++) {
        int i = base + threadIdx.x * 4 + k;
        if (i < N) { offsets[i] = excl; cursor[i] = excl; }
        excl += c[k];
    }
    if (b == gridDim.x - 1 && threadIdx.x == 255) offsets[N] = excl;
}

// Per-edge: geometry + scaled RBF once, 64 B record to CSR slot.
// r0={hx,hy,hz,scale} r1={rbfS0..3} r2={rbfS4..7} r3={j_bits,-,-,-}
__global__ __launch_bounds__(256) void fill_records(
    const float* __restrict__ rij,
    const int*   __restrict__ idx_i,
    const int*   __restrict__ idx_j,
    int*   __restrict__ cursor,
    float4* __restrict__ recs, int E)
{
    int e = blockIdx.x * blockDim.x + threadIdx.x;
    if (e >= E) return;

    float rx = rij[e * 3 + 0], ry = rij[e * 3 + 1], rz = rij[e * 3 + 2];
    float dn = sqrtf(rx * rx + ry * ry + rz * rz);
    float d = fmaxf(dn, 1e-6f);
    float inv = 1.0f / d;

    float rbf[NBASIS];
#pragma unroll
    for (int k = 0; k < NBASIS; k++) {
        float ck = 5.0f * (float)k / (float)(NBASIS - 1);
        float del = d - ck;
        rbf[k] = __expf(-4.0f * del * del);
    }
    float dc = fminf(d, 5.0f);
    float fc = 0.5f * (__cosf((float)M_PI * dc * 0.2f) + 1.0f);
    float scale = fc * 0.1f;   // cutoff * 1/NORM_FACTOR folded into filters

    int pos = atomicAdd(&cursor[idx_i[e]], 1);
    float4* r = recs + 4 * (size_t)pos;
    r[0] = make_float4(rx * inv, ry * inv, rz * inv, scale);
    r[1] = make_float4(rbf[0] * scale, rbf[1] * scale, rbf[2] * scale, rbf[3] * scale);
    r[2] = make_float4(rbf[4] * scale, rbf[5] * scale, rbf[6] * scale, rbf[7] * scale);
    r[3] = make_float4(__int_as_float(idx_j[e]), 0.0f, 0.0f, 0.0f);
}

struct Rec { float4 c0, c1, c2; int j; };

__device__ __forceinline__ Rec load_rec(const float4* __restrict__ recs, int k) {
    const float4* r = recs + 4 * (size_t)k;
    Rec o;
    o.c0 = r[0]; o.c1 = r[1]; o.c2 = r[2];
    o.j  = __float_as_int(r[3].x);
    return o;
}

__device__ __forceinline__ void gather13(float* __restrict__ G, int j, int c,
                                         const float* __restrict__ x0,
                                         const float* __restrict__ x1,
                                         const float* __restrict__ x2) {
    int base = j * CH + c;
    G[0] = x0[base];
#pragma unroll
    for (int a = 0; a < 3; a++) G[1 + a] = x1[base * 3 + a];
#pragma unroll
    for (int q = 0; q < 9; q++) G[4 + q] = x2[base * 9 + q];
}

// ---------- fused gather + self-interaction ----------
// 4 nodes per 256-block, one wave per node. Lanes 0-31: even CSR slots,
// lanes 32-63: odd. 2-deep software pipeline: next edge's gathers issue
// before current edge's compute. NO launch_bounds VGPR cap (R4 lesson:
// capping this body to 64 VGPR spills the pipeline arrays -> 1 GB traffic).
__global__ void fused_kernel(
    const float4* __restrict__ recs,
    const float* __restrict__ x0,      // [N,C]
    const float* __restrict__ x1,      // [N,C,3]
    const float* __restrict__ x2,      // [N,C,9]
    const int*   __restrict__ offsets, // [N+1]
    const float* __restrict__ W_rbf,   // [NBASIS, NPATH*C]
    const float* __restrict__ b_rbf,   // [NPATH*C]
    const float* __restrict__ Wmix0, const float* __restrict__ Wmix1, const float* __restrict__ Wmix2,
    const float* __restrict__ coupling,
    const float* __restrict__ Wg0, const float* __restrict__ Wg1, const float* __restrict__ Wg2,
    const float* __restrict__ bg0, const float* __restrict__ bg1, const float* __restrict__ bg2,
    float* __restrict__ out, int N)
{
    const int NW = 4;
    __shared__ float sa0[NW][CH];
    __shared__ float sa1[NW][CH][3];
    __shared__ float sa2[NW][CH][9];
    __shared__ float sy0[NW][CH];

    int wid  = threadIdx.x >> 6;
    int lane = threadIdx.x & 63;
    int half = lane >> 5;
    int c    = lane & 31;
    int n    = blockIdx.x * NW + wid;
    bool valid = (n < N);

    float A0 = 0.0f, A1[3] = {0, 0, 0}, A2[9] = {0, 0, 0, 0, 0, 0, 0, 0, 0};

    int kbeg = 0, kend = 0;
    if (valid) { kbeg = offsets[n]; kend = offsets[n + 1]; }

    int k = kbeg + half;
    bool h0 = (k < kend);
    bool h1 = (k + 2 < kend);
    Rec rc, rn;
    float G[13], Gn[13];
    if (h0) rc = load_rec(recs, k);
    if (h1) rn = load_rec(recs, k + 2);
    if (h0) gather13(G, rc.j, c, x0, x1, x2);

    while (h0) {
        // next edge's gathers + next-next record, before current compute
        if (h1) gather13(Gn, rn.j, c, x0, x1, x2);
        bool h2 = (k + 4 < kend);
        Rec rnn;
        if (h2) rnn = load_rec(recs, k + 4);

        // ---- filters for current edge ----
        float f[NPATH];
#pragma unroll
        for (int p = 0; p < NPATH; p++) {
            int col = p * CH + c;
            float acc = rc.c0.w * b_rbf[col];
            acc = fmaf(rc.c1.x, W_rbf[0 * (NPATH * CH) + col], acc);
            acc = fmaf(rc.c1.y, W_rbf[1 * (NPATH * CH) + col], acc);
            acc = fmaf(rc.c1.z, W_rbf[2 * (NPATH * CH) + col], acc);
            acc = fmaf(rc.c1.w, W_rbf[3 * (NPATH * CH) + col], acc);
            acc = fmaf(rc.c2.x, W_rbf[4 * (NPATH * CH) + col], acc);
            acc = fmaf(rc.c2.y, W_rbf[5 * (NPATH * CH) + col], acc);
            acc = fmaf(rc.c2.z, W_rbf[6 * (NPATH * CH) + col], acc);
            acc = fmaf(rc.c2.w, W_rbf[7 * (NPATH * CH) + col], acc);
            f[p] = acc;
        }

        float hv[3] = {rc.c0.x, rc.c0.y, rc.c0.z};
        float xj0 = G[0];
        float xv[3] = {G[1], G[2], G[3]};
        float x1r = xv[0] * hv[0] + xv[1] * hv[1] + xv[2] * hv[2];
        float x2r[3];
#pragma unroll
        for (int a = 0; a < 3; a++)
            x2r[a] = G[4 + a * 3 + 0] * hv[0] + G[4 + a * 3 + 1] * hv[1] + G[4 + a * 3 + 2] * hv[2];
        float x2rr = x2r[0] * hv[0] + x2r[1] * hv[1] + x2r[2] * hv[2];

        A0 += f[0] * xj0 + f[5] * x1r + f[10] * x2rr;

        float s01 = f[1] * xj0 + f[6] * x1r;
#pragma unroll
        for (int a = 0; a < 3; a++)
            A1[a] += s01 * hv[a] + f[3] * xv[a] + f[8] * x2r[a];

        float f2x = f[2] * xj0;
#pragma unroll
        for (int a = 0; a < 3; a++) {
            float w = f2x * hv[a] + f[4] * xv[a] + f[9] * x2r[a];
#pragma unroll
            for (int b = 0; b < 3; b++)
                A2[a * 3 + b] += w * hv[b] + f[7] * G[4 + a * 3 + b];
        }

        // rotate pipeline
        rc = rn; rn = rnn;
#pragma unroll
        for (int q = 0; q < 13; q++) G[q] = Gn[q];
        h0 = h1; h1 = h2; k += 2;
    }

    // combine halves -> all 64 lanes hold full sums
    A0 += __shfl_xor(A0, 32);
#pragma unroll
    for (int a = 0; a < 3; a++) A1[a] += __shfl_xor(A1[a], 32);
#pragma unroll
    for (int q = 0; q < 9; q++) A2[q] += __shfl_xor(A2[q], 32);

    if (half == 0) {
        sa0[wid][c] = A0;
#pragma unroll
        for (int a = 0; a < 3; a++) sa1[wid][c][a] = A1[a];
    } else {
#pragma unroll
        for (int q = 0; q < 9; q++) sa2[wid][c][q] = A2[q];
    }
    __syncthreads();

    int d = c;
    float y1[3] = {0, 0, 0};
    float y2[9] = {0, 0, 0, 0, 0, 0, 0, 0, 0};

    if (valid && half == 0) {
        float y0 = 0.0f;
#pragma unroll 8
        for (int cc = 0; cc < CH; cc++) y0 = fmaf(sa0[wid][cc], Wmix0[cc * CH + d], y0);
        float cp0 = coupling[0 * CH + d], cp3 = coupling[3 * CH + d], cp6 = coupling[6 * CH + d];
        float n1v = A1[0] * A1[0] + A1[1] * A1[1] + A1[2] * A1[2];
        float n2v = 0.0f;
#pragma unroll
        for (int q = 0; q < 9; q++) n2v = fmaf(A2[q], A2[q], n2v);
        y0 += cp0 * A0 * A0 + cp3 * n1v + cp6 * n2v;
        sy0[wid][d] = y0;

#pragma unroll 4
        for (int cc = 0; cc < CH; cc++) {
            float w = Wmix1[cc * CH + d];
#pragma unroll
            for (int a = 0; a < 3; a++) y1[a] = fmaf(sa1[wid][cc][a], w, y1[a]);
        }
        float cp1 = coupling[1 * CH + d], cp5 = coupling[5 * CH + d];
#pragma unroll
        for (int a = 0; a < 3; a++) {
            float a2a1 = A2[a * 3 + 0] * A1[0] + A2[a * 3 + 1] * A1[1] + A2[a * 3 + 2] * A1[2];
            y1[a] += cp1 * A0 * A1[a] + cp5 * a2a1;
        }
    } else if (valid) {
#pragma unroll 2
        for (int cc = 0; cc < CH; cc++) {
            float w = Wmix2[cc * CH + d];
#pragma unroll
            for (int q = 0; q < 9; q++) y2[q] = fmaf(sa2[wid][cc][q], w, y2[q]);
        }
        float cp2 = coupling[2 * CH + d], cp4 = coupling[4 * CH + d], cp7 = coupling[7 * CH + d];
#pragma unroll
        for (int a = 0; a < 3; a++) {
#pragma unroll
            for (int b = 0; b < 3; b++) {
                float a2a2 = A2[a * 3 + 0] * A2[0 * 3 + b] + A2[a * 3 + 1] * A2[1 * 3 + b]
                           + A2[a * 3 + 2] * A2[2 * 3 + b];
                y2[a * 3 + b] += cp2 * A0 * A2[a * 3 + b] + cp4 * A1[a] * A1[b] + cp7 * a2a2;
            }
        }
    }
    __syncthreads();  // sy0 ready

    if (valid && half == 0) {
        float g0 = bg0[d], g1 = bg1[d];
#pragma unroll 8
        for (int cc = 0; cc < CH; cc++) {
            float yv = sy0[wid][cc];
            g0 = fmaf(yv, Wg0[cc * CH + d], g0);
            g1 = fmaf(yv, Wg1[cc * CH + d], g1);
        }
        g0 = silu_f(g0);
        g1 = silu_f(g1);
        float* o = &out[(size_t)(n * CH + d) * 13];
        o[0] = x0[n * CH + d] + g0;
#pragma unroll
        for (int a = 0; a < 3; a++) o[1 + a] = x1[(n * CH + d) * 3 + a] + y1[a] * g1;
    } else if (valid) {
        float g2 = bg2[d];
#pragma unroll 8
        for (int cc = 0; cc < CH; cc++) g2 = fmaf(sy0[wid][cc], Wg2[cc * CH + d], g2);
        g2 = silu_f(g2);
        float* o = &out[(size_t)(n * CH + d) * 13];
#pragma unroll
        for (int q = 0; q < 9; q++) o[4 + q] = x2[(n * CH + d) * 9 + q] + y2[q] * g2;
    }
}

extern "C" void kernel_launch(void* const* d_in, const int* in_sizes, int n_in,
                              void* d_out, int out_size, void* d_ws, size_t ws_size,
                              hipStream_t stream) {
    const float* rij      = (const float*)d_in[0];
    const float* x0       = (const float*)d_in[1];
    const float* x1       = (const float*)d_in[2];
    const float* x2       = (const float*)d_in[3];
    const int*   idx_i    = (const int*)d_in[4];
    const int*   idx_j    = (const int*)d_in[5];
    const float* W_rbf    = (const float*)d_in[6];
    const float* b_rbf    = (const float*)d_in[7];
    const float* Wmix0    = (const float*)d_in[8];
    const float* Wmix1    = (const float*)d_in[9];
    const float* Wmix2    = (const float*)d_in[10];
    const float* coupling = (const float*)d_in[11];
    const float* Wg0      = (const float*)d_in[12];
    const float* Wg1      = (const float*)d_in[13];
    const float* Wg2      = (const float*)d_in[14];
    const float* bg0      = (const float*)d_in[15];
    const float* bg1      = (const float*)d_in[16];
    const float* bg2      = (const float*)d_in[17];

    int E = in_sizes[4];
    int N = in_sizes[1] / CH;
    int nsb = (N + 1023) / 1024;

    // ws: recs[E*4 float4] | counts[N] | offsets[N+1] | cursor[N] | bsum | bbase
    float4* recs = (float4*)d_ws;
    int* counts  = (int*)(recs + (size_t)E * 4);
    int* offsets = counts + N;
    int* cursor  = offsets + (N + 1);
    int* bsum    = cursor + N;
    int* bbase   = bsum + nsb;

    hipMemsetAsync(counts, 0, (size_t)N * sizeof(int), stream);

    int eblocks = (E + 255) / 256;
    hist_kernel<<<eblocks, 256, 0, stream>>>(idx_i, counts, E);
    partial_kernel<<<nsb, 256, 0, stream>>>(counts, bsum, N);
    scan_small<<<1, 64, 0, stream>>>(bsum, bbase, nsb);
    offsets_kernel<<<nsb, 256, 0, stream>>>(counts, bbase, offsets, cursor, N);
    fill_records<<<eblocks, 256, 0, stream>>>(rij, idx_i, idx_j, cursor, recs, E);

    fused_kernel<<<(N + 3) / 4, 256, 0, stream>>>(recs, x0, x1, x2, offsets,
                                                  W_rbf, b_rbf, Wmix0, Wmix1, Wmix2, coupling,
                                                  Wg0, Wg1, Wg2, bg0, bg1, bg2,
                                                  (float*)d_out, N);
}

// Round 7
// 314.390 us; speedup vs baseline: 2.2466x; 2.2466x over previous
//
#include <hip/hip_runtime.h>
#include <cmath>

#define CH 32
#define NBASIS 8
#define NPATH 11

__device__ __forceinline__ float silu_f(float x) {
    return x / (1.0f + __expf(-x));
}

// ---------- CSR build ----------
__global__ __launch_bounds__(256) void hist_kernel(const int* __restrict__ idx_i,
                                                   int* __restrict__ counts, int E) {
    int e = blockIdx.x * blockDim.x + threadIdx.x;
    if (e < E) atomicAdd(&counts[idx_i[e]], 1);
}

// 1024 counts per block -> bsum[b]
__global__ __launch_bounds__(256) void partial_kernel(const int* __restrict__ counts,
                                                      int* __restrict__ bsum, int N) {
    int base = blockIdx.x * 1024;
    int s = 0;
#pragma unroll
    for (int k = 0; k < 4; k++) {
        int i = base + k * 256 + threadIdx.x;
        if (i < N) s += counts[i];
    }
#pragma unroll
    for (int off = 32; off > 0; off >>= 1) s += __shfl_down(s, off);
    __shared__ int wsum[4];
    if ((threadIdx.x & 63) == 0) wsum[threadIdx.x >> 6] = s;
    __syncthreads();
    if (threadIdx.x == 0) bsum[blockIdx.x] = wsum[0] + wsum[1] + wsum[2] + wsum[3];
}

__global__ void scan_small(const int* __restrict__ bsum, int* __restrict__ bbase, int nb) {
    if (threadIdx.x == 0) {
        int acc = 0;
        for (int i = 0; i < nb; i++) { bbase[i] = acc; acc += bsum[i]; }
    }
}

__global__ __launch_bounds__(256) void offsets_kernel(const int* __restrict__ counts,
                                                      const int* __restrict__ bbase,
                                                      int* __restrict__ offsets,
                                                      int* __restrict__ cursor, int N) {
    int b = blockIdx.x;
    int base = b * 1024;
    int c[4];
    int s = 0;
#pragma unroll
    for (int k = 0; k < 4; k++) {
        int i = base + threadIdx.x * 4 + k;
        c[k] = (i < N) ? counts[i] : 0;
        s += c[k];
    }
    __shared__ int sc[256];
    sc[threadIdx.x] = s;
    __syncthreads();
    for (int off = 1; off < 256; off <<= 1) {
        int v = (threadIdx.x >= off) ? sc[threadIdx.x - off] : 0;
        __syncthreads();
        sc[threadIdx.x] += v;
        __syncthreads();
    }
    int excl = bbase[b] + sc[threadIdx.x] - s;
#pragma unroll
    for (int k = 0; k < 4; k++) {
        int i = base + threadIdx.x * 4 + k;
        if (i < N) { offsets[i] = excl; cursor[i] = excl; }
        excl += c[k];
    }
    if (b == gridDim.x - 1 && threadIdx.x == 255) offsets[N] = excl;
}

// Per-edge: geometry + scaled RBF once, 64 B record to CSR slot.
// r0={hx,hy,hz,scale} r1={rbfS0..3} r2={rbfS4..7} r3={j_bits,-,-,-}
__global__ __launch_bounds__(256) void fill_records(
    const float* __restrict__ rij,
    const int*   __restrict__ idx_i,
    const int*   __restrict__ idx_j,
    int*   __restrict__ cursor,
    float4* __restrict__ recs, int E)
{
    int e = blockIdx.x * blockDim.x + threadIdx.x;
    if (e >= E) return;

    float rx = rij[e * 3 + 0], ry = rij[e * 3 + 1], rz = rij[e * 3 + 2];
    float dn = sqrtf(rx * rx + ry * ry + rz * rz);
    float d = fmaxf(dn, 1e-6f);
    float inv = 1.0f / d;

    float rbf[NBASIS];
#pragma unroll
    for (int k = 0; k < NBASIS; k++) {
        float ck = 5.0f * (float)k / (float)(NBASIS - 1);
        float del = d - ck;
        rbf[k] = __expf(-4.0f * del * del);
    }
    float dc = fminf(d, 5.0f);
    float fc = 0.5f * (__cosf((float)M_PI * dc * 0.2f) + 1.0f);
    float scale = fc * 0.1f;   // cutoff * 1/NORM_FACTOR folded into filters

    int pos = atomicAdd(&cursor[idx_i[e]], 1);
    float4* r = recs + 4 * (size_t)pos;
    r[0] = make_float4(rx * inv, ry * inv, rz * inv, scale);
    r[1] = make_float4(rbf[0] * scale, rbf[1] * scale, rbf[2] * scale, rbf[3] * scale);
    r[2] = make_float4(rbf[4] * scale, rbf[5] * scale, rbf[6] * scale, rbf[7] * scale);
    r[3] = make_float4(__int_as_float(idx_j[e]), 0.0f, 0.0f, 0.0f);
}

struct Rec { float4 c0, c1, c2; int j; };

__device__ __forceinline__ Rec load_rec(const float4* __restrict__ recs, int k) {
    const float4* r = recs + 4 * (size_t)k;
    Rec o;
    o.c0 = r[0]; o.c1 = r[1]; o.c2 = r[2];
    o.j  = __float_as_int(r[3].x);
    return o;
}

__device__ __forceinline__ void gather13(float* __restrict__ G, int j, int c,
                                         const float* __restrict__ x0,
                                         const float* __restrict__ x1,
                                         const float* __restrict__ x2) {
    int base = j * CH + c;
    G[0] = x0[base];
#pragma unroll
    for (int a = 0; a < 3; a++) G[1 + a] = x1[base * 3 + a];
#pragma unroll
    for (int q = 0; q < 9; q++) G[4 + q] = x2[base * 9 + q];
}

// ---------- fused gather + self-interaction ----------
// 4 nodes per 256-block, one wave per node. Lanes 0-31: even CSR slots,
// lanes 32-63: odd. 2-deep software pipeline: next edge's gathers issue
// before current edge's compute.
// __launch_bounds__(256, 1): authorize up to ~512 VGPRs. R4 (explicit cap 64)
// and R6 (compiler default heuristic ALSO chose 64) both spilled the pipeline
// arrays -> 1 GB FETCH / 400 MB WRITE. Spill tripwire: WRITE_SIZE >> 32.5 MB.
__global__ __launch_bounds__(256, 1) void fused_kernel(
    const float4* __restrict__ recs,
    const float* __restrict__ x0,      // [N,C]
    const float* __restrict__ x1,      // [N,C,3]
    const float* __restrict__ x2,      // [N,C,9]
    const int*   __restrict__ offsets, // [N+1]
    const float* __restrict__ W_rbf,   // [NBASIS, NPATH*C]
    const float* __restrict__ b_rbf,   // [NPATH*C]
    const float* __restrict__ Wmix0, const float* __restrict__ Wmix1, const float* __restrict__ Wmix2,
    const float* __restrict__ coupling,
    const float* __restrict__ Wg0, const float* __restrict__ Wg1, const float* __restrict__ Wg2,
    const float* __restrict__ bg0, const float* __restrict__ bg1, const float* __restrict__ bg2,
    float* __restrict__ out, int N)
{
    const int NW = 4;
    __shared__ float sa0[NW][CH];
    __shared__ float sa1[NW][CH][3];
    __shared__ float sa2[NW][CH][9];
    __shared__ float sy0[NW][CH];

    int wid  = threadIdx.x >> 6;
    int lane = threadIdx.x & 63;
    int half = lane >> 5;
    int c    = lane & 31;
    int n    = blockIdx.x * NW + wid;
    bool valid = (n < N);

    float A0 = 0.0f, A1[3] = {0, 0, 0}, A2[9] = {0, 0, 0, 0, 0, 0, 0, 0, 0};

    int kbeg = 0, kend = 0;
    if (valid) { kbeg = offsets[n]; kend = offsets[n + 1]; }

    int k = kbeg + half;
    bool h0 = (k < kend);
    bool h1 = (k + 2 < kend);
    Rec rc, rn;
    float G[13], Gn[13];
    if (h0) rc = load_rec(recs, k);
    if (h1) rn = load_rec(recs, k + 2);
    if (h0) gather13(G, rc.j, c, x0, x1, x2);

    while (h0) {
        // next edge's gathers + next-next record, before current compute
        if (h1) gather13(Gn, rn.j, c, x0, x1, x2);
        bool h2 = (k + 4 < kend);
        Rec rnn;
        if (h2) rnn = load_rec(recs, k + 4);

        // ---- filters for current edge ----
        float f[NPATH];
#pragma unroll
        for (int p = 0; p < NPATH; p++) {
            int col = p * CH + c;
            float acc = rc.c0.w * b_rbf[col];
            acc = fmaf(rc.c1.x, W_rbf[0 * (NPATH * CH) + col], acc);
            acc = fmaf(rc.c1.y, W_rbf[1 * (NPATH * CH) + col], acc);
            acc = fmaf(rc.c1.z, W_rbf[2 * (NPATH * CH) + col], acc);
            acc = fmaf(rc.c1.w, W_rbf[3 * (NPATH * CH) + col], acc);
            acc = fmaf(rc.c2.x, W_rbf[4 * (NPATH * CH) + col], acc);
            acc = fmaf(rc.c2.y, W_rbf[5 * (NPATH * CH) + col], acc);
            acc = fmaf(rc.c2.z, W_rbf[6 * (NPATH * CH) + col], acc);
            acc = fmaf(rc.c2.w, W_rbf[7 * (NPATH * CH) + col], acc);
            f[p] = acc;
        }

        float hv[3] = {rc.c0.x, rc.c0.y, rc.c0.z};
        float xj0 = G[0];
        float xv[3] = {G[1], G[2], G[3]};
        float x1r = xv[0] * hv[0] + xv[1] * hv[1] + xv[2] * hv[2];
        float x2r[3];
#pragma unroll
        for (int a = 0; a < 3; a++)
            x2r[a] = G[4 + a * 3 + 0] * hv[0] + G[4 + a * 3 + 1] * hv[1] + G[4 + a * 3 + 2] * hv[2];
        float x2rr = x2r[0] * hv[0] + x2r[1] * hv[1] + x2r[2] * hv[2];

        A0 += f[0] * xj0 + f[5] * x1r + f[10] * x2rr;

        float s01 = f[1] * xj0 + f[6] * x1r;
#pragma unroll
        for (int a = 0; a < 3; a++)
            A1[a] += s01 * hv[a] + f[3] * xv[a] + f[8] * x2r[a];

        float f2x = f[2] * xj0;
#pragma unroll
        for (int a = 0; a < 3; a++) {
            float w = f2x * hv[a] + f[4] * xv[a] + f[9] * x2r[a];
#pragma unroll
            for (int b = 0; b < 3; b++)
                A2[a * 3 + b] += w * hv[b] + f[7] * G[4 + a * 3 + b];
        }

        // rotate pipeline
        rc = rn; rn = rnn;
#pragma unroll
        for (int q = 0; q < 13; q++) G[q] = Gn[q];
        h0 = h1; h1 = h2; k += 2;
    }

    // combine halves -> all 64 lanes hold full sums
    A0 += __shfl_xor(A0, 32);
#pragma unroll
    for (int a = 0; a < 3; a++) A1[a] += __shfl_xor(A1[a], 32);
#pragma unroll
    for (int q = 0; q < 9; q++) A2[q] += __shfl_xor(A2[q], 32);

    if (half == 0) {
        sa0[wid][c] = A0;
#pragma unroll
        for (int a = 0; a < 3; a++) sa1[wid][c][a] = A1[a];
    } else {
#pragma unroll
        for (int q = 0; q < 9; q++) sa2[wid][c][q] = A2[q];
    }
    __syncthreads();

    int d = c;
    float y1[3] = {0, 0, 0};
    float y2[9] = {0, 0, 0, 0, 0, 0, 0, 0, 0};

    if (valid && half == 0) {
        float y0 = 0.0f;
#pragma unroll 8
        for (int cc = 0; cc < CH; cc++) y0 = fmaf(sa0[wid][cc], Wmix0[cc * CH + d], y0);
        float cp0 = coupling[0 * CH + d], cp3 = coupling[3 * CH + d], cp6 = coupling[6 * CH + d];
        float n1v = A1[0] * A1[0] + A1[1] * A1[1] + A1[2] * A1[2];
        float n2v = 0.0f;
#pragma unroll
        for (int q = 0; q < 9; q++) n2v = fmaf(A2[q], A2[q], n2v);
        y0 += cp0 * A0 * A0 + cp3 * n1v + cp6 * n2v;
        sy0[wid][d] = y0;

#pragma unroll 4
        for (int cc = 0; cc < CH; cc++) {
            float w = Wmix1[cc * CH + d];
#pragma unroll
            for (int a = 0; a < 3; a++) y1[a] = fmaf(sa1[wid][cc][a], w, y1[a]);
        }
        float cp1 = coupling[1 * CH + d], cp5 = coupling[5 * CH + d];
#pragma unroll
        for (int a = 0; a < 3; a++) {
            float a2a1 = A2[a * 3 + 0] * A1[0] + A2[a * 3 + 1] * A1[1] + A2[a * 3 + 2] * A1[2];
            y1[a] += cp1 * A0 * A1[a] + cp5 * a2a1;
        }
    } else if (valid) {
#pragma unroll 2
        for (int cc = 0; cc < CH; cc++) {
            float w = Wmix2[cc * CH + d];
#pragma unroll
            for (int q = 0; q < 9; q++) y2[q] = fmaf(sa2[wid][cc][q], w, y2[q]);
        }
        float cp2 = coupling[2 * CH + d], cp4 = coupling[4 * CH + d], cp7 = coupling[7 * CH + d];
#pragma unroll
        for (int a = 0; a < 3; a++) {
#pragma unroll
            for (int b = 0; b < 3; b++) {
                float a2a2 = A2[a * 3 + 0] * A2[0 * 3 + b] + A2[a * 3 + 1] * A2[1 * 3 + b]
                           + A2[a * 3 + 2] * A2[2 * 3 + b];
                y2[a * 3 + b] += cp2 * A0 * A2[a * 3 + b] + cp4 * A1[a] * A1[b] + cp7 * a2a2;
            }
        }
    }
    __syncthreads();  // sy0 ready

    if (valid && half == 0) {
        float g0 = bg0[d], g1 = bg1[d];
#pragma unroll 8
        for (int cc = 0; cc < CH; cc++) {
            float yv = sy0[wid][cc];
            g0 = fmaf(yv, Wg0[cc * CH + d], g0);
            g1 = fmaf(yv, Wg1[cc * CH + d], g1);
        }
        g0 = silu_f(g0);
        g1 = silu_f(g1);
        float* o = &out[(size_t)(n * CH + d) * 13];
        o[0] = x0[n * CH + d] + g0;
#pragma unroll
        for (int a = 0; a < 3; a++) o[1 + a] = x1[(n * CH + d) * 3 + a] + y1[a] * g1;
    } else if (valid) {
        float g2 = bg2[d];
#pragma unroll 8
        for (int cc = 0; cc < CH; cc++) g2 = fmaf(sy0[wid][cc], Wg2[cc * CH + d], g2);
        g2 = silu_f(g2);
        float* o = &out[(size_t)(n * CH + d) * 13];
#pragma unroll
        for (int q = 0; q < 9; q++) o[4 + q] = x2[(n * CH + d) * 9 + q] + y2[q] * g2;
    }
}

extern "C" void kernel_launch(void* const* d_in, const int* in_sizes, int n_in,
                              void* d_out, int out_size, void* d_ws, size_t ws_size,
                              hipStream_t stream) {
    const float* rij      = (const float*)d_in[0];
    const float* x0       = (const float*)d_in[1];
    const float* x1       = (const float*)d_in[2];
    const float* x2       = (const float*)d_in[3];
    const int*   idx_i    = (const int*)d_in[4];
    const int*   idx_j    = (const int*)d_in[5];
    const float* W_rbf    = (const float*)d_in[6];
    const float* b_rbf    = (const float*)d_in[7];
    const float* Wmix0    = (const float*)d_in[8];
    const float* Wmix1    = (const float*)d_in[9];
    const float* Wmix2    = (const float*)d_in[10];
    const float* coupling = (const float*)d_in[11];
    const float* Wg0      = (const float*)d_in[12];
    const float* Wg1      = (const float*)d_in[13];
    const float* Wg2      = (const float*)d_in[14];
    const float* bg0      = (const float*)d_in[15];
    const float* bg1      = (const float*)d_in[16];
    const float* bg2      = (const float*)d_in[17];

    int E = in_sizes[4];
    int N = in_sizes[1] / CH;
    int nsb = (N + 1023) / 1024;

    // ws: recs[E*4 float4] | counts[N] | offsets[N+1] | cursor[N] | bsum | bbase
    float4* recs = (float4*)d_ws;
    int* counts  = (int*)(recs + (size_t)E * 4);
    int* offsets = counts + N;
    int* cursor  = offsets + (N + 1);
    int* bsum    = cursor + N;
    int* bbase   = bsum + nsb;

    hipMemsetAsync(counts, 0, (size_t)N * sizeof(int), stream);

    int eblocks = (E + 255) / 256;
    hist_kernel<<<eblocks, 256, 0, stream>>>(idx_i, counts, E);
    partial_kernel<<<nsb, 256, 0, stream>>>(counts, bsum, N);
    scan_small<<<1, 64, 0, stream>>>(bsum, bbase, nsb);
    offsets_kernel<<<nsb, 256, 0, stream>>>(counts, bbase, offsets, cursor, N);
    fill_records<<<eblocks, 256, 0, stream>>>(rij, idx_i, idx_j, cursor, recs, E);

    fused_kernel<<<(N + 3) / 4, 256, 0, stream>>>(recs, x0, x1, x2, offsets,
                                                  W_rbf, b_rbf, Wmix0, Wmix1, Wmix2, coupling,
                                                  Wg0, Wg1, Wg2, bg0, bg1, bg2,
                                                  (float*)d_out, N);
}